// Round 8
// baseline (183.452 us; speedup 1.0000x reference)
//
#include <hip/hip_runtime.h>
#include <math.h>

// Amortized VI, two-kernel split:
//  A: per-row MLP params (weights amortized over 4 rows/thread, packed v2)
//  B: per-row 8-sample Cholesky+FK tail (no weights, TLP-hidden memory)
//
// R7 insight: perf tracks rows-per-thread (weight s_load amortization), not
// occupancy: R3/R7 1-row=51us, R4 2-row=46, R5 packed=43, R6 +prefetch=37.
// The stall is the per-wave s_load->lgkm->FMA chain; more independent FMAs
// per weight covers it. Split lets A use 4 rows/thread without tail VGPR.
//
// Constants folded: C_PRIOR + C_LIK + C_ENT = 12.838199208
#define C_ALL 12.838199208f

typedef float v2 __attribute__((ext_vector_type(2)));
static __device__ __forceinline__ v2 splat(float s) { return (v2){s, s}; }
#define FMA2 __builtin_elementwise_fma
#define MAX2 __builtin_elementwise_max

struct WPtrs { const float* p[18]; };

__device__ __forceinline__ float softplus_f(float x) {
    return fmaxf(x, 0.0f) + __logf(1.0f + __expf(-fabsf(x)));
}
__device__ __forceinline__ v2 sp2(v2 x) {
    v2 r; r.x = softplus_f(x.x); r.y = softplus_f(x.y); return r;
}

// 4-row MLP (two packed v2 pairs); every scalar weight feeds 4 FMAs (2 VOP3P).
template <int OD>
__device__ __forceinline__ void mlp4(const float* __restrict__ W1,
                                     const float* __restrict__ b1,
                                     const float* __restrict__ W2,
                                     const float* __restrict__ b2,
                                     const float* __restrict__ W3,
                                     const float* __restrict__ b3,
                                     v2 Y0a, v2 Y1a, v2 Y0b, v2 Y1b,
                                     v2* oa, v2* ob) {
    v2 h2a[10], h2b[10];
#pragma unroll
    for (int k = 0; k < 10; ++k) { const v2 bb = splat(b2[k]); h2a[k] = bb; h2b[k] = bb; }
#pragma unroll
    for (int j = 0; j < 20; ++j) {
        const float w0 = W1[j], w1 = W1[20 + j], bb = b1[j];
        const v2 h1a = MAX2(FMA2(Y0a, splat(w0), FMA2(Y1a, splat(w1), splat(bb))), splat(0.0f));
        const v2 h1b = MAX2(FMA2(Y0b, splat(w0), FMA2(Y1b, splat(w1), splat(bb))), splat(0.0f));
#pragma unroll
        for (int k = 0; k < 10; ++k) {
            const v2 w = splat(W2[j * 10 + k]);
            h2a[k] = FMA2(h1a, w, h2a[k]);
            h2b[k] = FMA2(h1b, w, h2b[k]);
        }
    }
#pragma unroll
    for (int k = 0; k < 10; ++k) { h2a[k] = MAX2(h2a[k], splat(0.0f)); h2b[k] = MAX2(h2b[k], splat(0.0f)); }
#pragma unroll
    for (int d = 0; d < OD; ++d) { const v2 bb = splat(b3[d]); oa[d] = bb; ob[d] = bb; }
#pragma unroll
    for (int k = 0; k < 10; ++k) {
#pragma unroll
        for (int d = 0; d < OD; ++d) {
            const v2 w = splat(W3[k * OD + d]);
            oa[d] = FMA2(h2a[k], w, oa[d]);
            ob[d] = FMA2(h2b[k], w, ob[d]);
        }
    }
}

// scalar MLP for the (never-hit at N=524288) tail guard
template <int OD>
__device__ __forceinline__ void mlp1(const float* __restrict__ W1, const float* __restrict__ b1,
                                     const float* __restrict__ W2, const float* __restrict__ b2,
                                     const float* __restrict__ W3, const float* __restrict__ b3,
                                     float y0, float y1, float* out) {
    float h2[10];
#pragma unroll
    for (int k = 0; k < 10; ++k) h2[k] = b2[k];
#pragma unroll
    for (int j = 0; j < 20; ++j) {
        const float h1 = fmaxf(0.0f, fmaf(y0, W1[j], fmaf(y1, W1[20 + j], b1[j])));
#pragma unroll
        for (int k = 0; k < 10; ++k) h2[k] = fmaf(h1, W2[j * 10 + k], h2[k]);
    }
#pragma unroll
    for (int k = 0; k < 10; ++k) h2[k] = fmaxf(0.0f, h2[k]);
#pragma unroll
    for (int d = 0; d < OD; ++d) out[d] = b3[d];
#pragma unroll
    for (int k = 0; k < 10; ++k)
#pragma unroll
        for (int d = 0; d < OD; ++d) out[d] = fmaf(h2[k], W3[k * OD + d], out[d]);
}

__device__ __forceinline__ void store_params(float* __restrict__ pr, int row,
                                             float m0, float m1, float m2, float m3,
                                             float d0, float d1, float d2, float d3,
                                             float L10, float L20, float L21,
                                             float L30, float L31, float L32) {
    float4* q = reinterpret_cast<float4*>(pr + (size_t)row * 16);
    q[0] = make_float4(m0, m1, m2, m3);
    q[1] = make_float4(d0, d1, d2, d3);
    q[2] = make_float4(L10, L20, L21, L30);
    q[3] = make_float4(L31, L32, __logf(d0 * d1 * d2 * d3), 0.0f);
}

// ---------------- Kernel A: params (4 rows/thread) ----------------
__global__ __launch_bounds__(256) void avi_params(
    const float* __restrict__ y, WPtrs wp, float* __restrict__ pr, int N) {
    const int tid = threadIdx.x;
    const int r0 = blockIdx.x * 1024 + tid;  // rows r0, +256, +512, +768

    if (r0 + 768 < N) {
        const float2 ya = *reinterpret_cast<const float2*>(y + 2 * (size_t)(r0));
        const float2 yb = *reinterpret_cast<const float2*>(y + 2 * (size_t)(r0 + 256));
        const float2 yc = *reinterpret_cast<const float2*>(y + 2 * (size_t)(r0 + 512));
        const float2 yd = *reinterpret_cast<const float2*>(y + 2 * (size_t)(r0 + 768));
        const v2 Y0a = {ya.x, yb.x}, Y1a = {ya.y, yb.y};
        const v2 Y0b = {yc.x, yd.x}, Y1b = {yc.y, yd.y};

        v2 mua[4], mub[4], lda[4], ldb[4], loa[6], lob[6];
        mlp4<4>(wp.p[0], wp.p[1], wp.p[2], wp.p[3], wp.p[4], wp.p[5],
                Y0a, Y1a, Y0b, Y1b, mua, mub);
        mlp4<4>(wp.p[6], wp.p[7], wp.p[8], wp.p[9], wp.p[10], wp.p[11],
                Y0a, Y1a, Y0b, Y1b, lda, ldb);
        mlp4<6>(wp.p[12], wp.p[13], wp.p[14], wp.p[15], wp.p[16], wp.p[17],
                Y0a, Y1a, Y0b, Y1b, loa, lob);

        const v2 da0 = sp2(lda[0]), da1 = sp2(lda[1]), da2 = sp2(lda[2]), da3 = sp2(lda[3]);
        const v2 db0 = sp2(ldb[0]), db1 = sp2(ldb[1]), db2 = sp2(ldb[2]), db3 = sp2(ldb[3]);

        store_params(pr, r0,       mua[0].x, mua[1].x, mua[2].x, mua[3].x,
                     da0.x, da1.x, da2.x, da3.x,
                     loa[0].x, loa[1].x, loa[2].x, loa[3].x, loa[4].x, loa[5].x);
        store_params(pr, r0 + 256, mua[0].y, mua[1].y, mua[2].y, mua[3].y,
                     da0.y, da1.y, da2.y, da3.y,
                     loa[0].y, loa[1].y, loa[2].y, loa[3].y, loa[4].y, loa[5].y);
        store_params(pr, r0 + 512, mub[0].x, mub[1].x, mub[2].x, mub[3].x,
                     db0.x, db1.x, db2.x, db3.x,
                     lob[0].x, lob[1].x, lob[2].x, lob[3].x, lob[4].x, lob[5].x);
        store_params(pr, r0 + 768, mub[0].y, mub[1].y, mub[2].y, mub[3].y,
                     db0.y, db1.y, db2.y, db3.y,
                     lob[0].y, lob[1].y, lob[2].y, lob[3].y, lob[4].y, lob[5].y);
    } else {
        for (int s = 0; s < 4; ++s) {
            const int row = r0 + s * 256;
            if (row >= N) continue;
            const float2 yv = *reinterpret_cast<const float2*>(y + 2 * (size_t)row);
            float mu[4], ld[4], lo[6];
            mlp1<4>(wp.p[0], wp.p[1], wp.p[2], wp.p[3], wp.p[4], wp.p[5], yv.x, yv.y, mu);
            mlp1<4>(wp.p[6], wp.p[7], wp.p[8], wp.p[9], wp.p[10], wp.p[11], yv.x, yv.y, ld);
            mlp1<6>(wp.p[12], wp.p[13], wp.p[14], wp.p[15], wp.p[16], wp.p[17], yv.x, yv.y, lo);
            store_params(pr, row, mu[0], mu[1], mu[2], mu[3],
                         softplus_f(ld[0]), softplus_f(ld[1]), softplus_f(ld[2]), softplus_f(ld[3]),
                         lo[0], lo[1], lo[2], lo[3], lo[4], lo[5]);
        }
    }
}

// ---------------- Kernel B: tail (1 row/thread, no weights) ----------------
__global__ __launch_bounds__(256) void avi_tail(
    const float* __restrict__ y, const float* __restrict__ zs,
    const float* __restrict__ pr, float* __restrict__ out, int N, float invN) {
    __shared__ float wsum[4];
    const int tid = threadIdx.x;
    const int n = blockIdx.x * 256 + tid;
    float rv = 0.0f;
    if (n < N) {
        const float4* pq = reinterpret_cast<const float4*>(pr + (size_t)n * 16);
        const float4 p0 = pq[0], p1 = pq[1], p2 = pq[2], p3 = pq[3];
        const float2 yv = *reinterpret_cast<const float2*>(y + 2 * (size_t)n);
        const float y0 = yv.x, y1 = yv.y;

        const float4* zp = reinterpret_cast<const float4*>(zs + (size_t)n * 32);
        float4 z[8];
#pragma unroll
        for (int p = 0; p < 8; ++p) z[p] = zp[p];
        __builtin_amdgcn_sched_barrier(0);

        const float m0 = p0.x, m1 = p0.y, m2 = p0.z, m3 = p0.w;
        const float d0 = p1.x, d1 = p1.y, d2 = p1.z, d3 = p1.w;
        const float L10 = p2.x, L20 = p2.y, L21 = p2.z, L30 = p2.w;
        const float L31 = p3.x, L32 = p3.y, slog = p3.z;

        float acc = 0.0f;
#pragma unroll
        for (int p = 0; p < 8; ++p) {
            const float xi0 = fmaf(d0, z[p].x, m0);
            const float xi1 = fmaf(d1, z[p].y, fmaf(L10, z[p].x, m1));
            const float xi2 = fmaf(d2, z[p].z, fmaf(L21, z[p].y, fmaf(L20, z[p].x, m2)));
            const float xi3 = fmaf(d3, z[p].w, fmaf(L32, z[p].z, fmaf(L31, z[p].y, fmaf(L30, z[p].x, m3))));

            const float a1 = xi1, a2 = xi1 + xi2, a3 = a2 + xi3;
            float s1, c1, s2, c2, s3, c3;
            __sincosf(a1, &s1, &c1);
            __sincosf(a2, &s2, &c2);
            __sincosf(a3, &s3, &c3);
            const float px = fmaf(0.5f, c1, fmaf(0.5f, c2, c3));
            const float py = xi0 + fmaf(0.5f, s1, fmaf(0.5f, s2, s3));

            const float q0 = xi0 * 4.0f, q1 = xi1 * 2.0f, q2 = xi2 * 2.0f, q3 = xi3 * 2.0f;
            const float pq2 = fmaf(q0, q0, fmaf(q1, q1, fmaf(q2, q2, q3 * q3)));
            const float r0 = (y0 - px) * 100.0f;
            const float r1 = (y1 - py) * 100.0f;
            acc = fmaf(-0.5f, pq2 + fmaf(r0, r0, r1 * r1), acc);
        }
        rv = fmaf(0.125f, acc, C_ALL + slog);
    }

#pragma unroll
    for (int d = 32; d > 0; d >>= 1) rv += __shfl_down(rv, d);
    if ((tid & 63) == 0) wsum[tid >> 6] = rv;
    __syncthreads();
    if (tid == 0) {
        const float s = wsum[0] + wsum[1] + wsum[2] + wsum[3];
        atomicAdd(out, s * invN);
    }
}

extern "C" void kernel_launch(void* const* d_in, const int* in_sizes, int n_in,
                              void* d_out, int out_size, void* d_ws, size_t ws_size,
                              hipStream_t stream) {
    const float* y = (const float*)d_in[0];
    const float* zs = (const float*)d_in[1];
    WPtrs wp;
    for (int i = 0; i < 18; ++i) wp.p[i] = (const float*)d_in[2 + i];
    float* out = (float*)d_out;
    float* pr = (float*)d_ws;  // N x 16 f32 = 32 MB << ws_size
    const int N = in_sizes[0] / 2;

    hipMemsetAsync(out, 0, sizeof(float), stream);
    avi_params<<<(N + 1023) / 1024, 256, 0, stream>>>(y, wp, pr, N);
    avi_tail<<<(N + 255) / 256, 256, 0, stream>>>(y, zs, pr, out, N, 1.0f / (float)N);
}

// Round 9
// 168.577 us; speedup vs baseline: 1.0882x; 1.0882x over previous
//
#include <hip/hip_runtime.h>
#include <math.h>

// Amortized VI: per-row 3 MLPs (2->20->10->{4,4,6}), Cholesky reparam over
// P=8 samples, robot-arm FK likelihood, global mean.
//
// R8 insight: two-kernel split regressed (ws round-trip + thin grid).
// Ladder: R3 1row=51, R4 2row=46, R5 2row-packed=43 (VGPR 44!), R6
// +prefetch=37 (VGPR ~110), all at <=16 waves/CU (grid- or VGPR-capped).
// Everything idle (VALU 26%, HBM 13%) -> latency-bound, too few waves.
// Fix: keep the lean R5 body (44 VGPR -> 8 waves/SIMD allocatable) and
// launch BLOCK=128 -> 2048 blocks = 32 waves/CU from the grid. Cross-wave
// TLP hides the in-loop z loads; no prefetch arrays (VGPR stays low).
//
// Constants folded: C_PRIOR + C_LIK + C_ENT = 12.838199208
#define C_ALL 12.838199208f

typedef float v2 __attribute__((ext_vector_type(2)));
static __device__ __forceinline__ v2 splat(float s) { return (v2){s, s}; }
#define FMA2 __builtin_elementwise_fma
#define MAX2 __builtin_elementwise_max

struct WPtrs { const float* p[18]; };

__device__ __forceinline__ float softplus_f(float x) {
    return fmaxf(x, 0.0f) + __logf(1.0f + __expf(-fabsf(x)));
}
__device__ __forceinline__ v2 sp2(v2 x) {
    v2 r; r.x = softplus_f(x.x); r.y = softplus_f(x.y); return r;
}

// Two-row packed MLP; weights wave-uniform (SGPR), broadcast into VOP3P.
// h1 fused into the j-loop: 1 live v2 temp instead of 20.
template <int OD>
__device__ __forceinline__ void mlp2(const float* __restrict__ W1,
                                     const float* __restrict__ b1,
                                     const float* __restrict__ W2,
                                     const float* __restrict__ b2,
                                     const float* __restrict__ W3,
                                     const float* __restrict__ b3,
                                     v2 Y0, v2 Y1, v2* out) {
    v2 h2[10];
#pragma unroll
    for (int k = 0; k < 10; ++k) h2[k] = splat(b2[k]);
#pragma unroll
    for (int j = 0; j < 20; ++j) {
        const v2 h1 = MAX2(FMA2(Y0, splat(W1[j]), FMA2(Y1, splat(W1[20 + j]), splat(b1[j]))),
                           splat(0.0f));
#pragma unroll
        for (int k = 0; k < 10; ++k) h2[k] = FMA2(h1, splat(W2[j * 10 + k]), h2[k]);
    }
#pragma unroll
    for (int k = 0; k < 10; ++k) h2[k] = MAX2(h2[k], splat(0.0f));
#pragma unroll
    for (int d = 0; d < OD; ++d) out[d] = splat(b3[d]);
#pragma unroll
    for (int k = 0; k < 10; ++k) {
#pragma unroll
        for (int d = 0; d < OD; ++d) out[d] = FMA2(h2[k], splat(W3[k * OD + d]), out[d]);
    }
}

__global__ __launch_bounds__(128) void avi_kernel(
    const float* __restrict__ y, const float* __restrict__ zs, WPtrs wp,
    float* __restrict__ out, int N, float invN) {
    __shared__ float wsum[2];

    const int tid = threadIdx.x;
    const int na = blockIdx.x * 256 + tid;   // row A
    const int nb = na + 128;                 // row B (coalesced second half-slab)
    float rv = 0.0f;
    if (na < N) {
        const int mb = (nb < N) ? nb : na;   // tail safety (not hit: N % 256 == 0)
        const float2 ya = *reinterpret_cast<const float2*>(y + 2 * (size_t)na);
        const float2 yb = *reinterpret_cast<const float2*>(y + 2 * (size_t)mb);
        const v2 Y0 = {ya.x, yb.x};
        const v2 Y1 = {ya.y, yb.y};

        v2 mu[4], ld[4], lo[6];
        mlp2<4>(wp.p[0], wp.p[1], wp.p[2], wp.p[3], wp.p[4], wp.p[5], Y0, Y1, mu);
        mlp2<4>(wp.p[6], wp.p[7], wp.p[8], wp.p[9], wp.p[10], wp.p[11], Y0, Y1, ld);
        mlp2<6>(wp.p[12], wp.p[13], wp.p[14], wp.p[15], wp.p[16], wp.p[17], Y0, Y1, lo);

        const v2 d0 = sp2(ld[0]), d1 = sp2(ld[1]), d2 = sp2(ld[2]), d3 = sp2(ld[3]);
        const v2 prod = d0 * d1 * d2 * d3;
        const v2 L10 = lo[0], L20 = lo[1], L21 = lo[2];
        const v2 L30 = lo[3], L31 = lo[4], L32 = lo[5];

        const float4* zpa = reinterpret_cast<const float4*>(zs + (size_t)na * 32);
        const float4* zpb = reinterpret_cast<const float4*>(zs + (size_t)mb * 32);
        v2 acc = splat(0.0f);
#pragma unroll
        for (int p = 0; p < 8; ++p) {
            const float4 za = zpa[p];
            const float4 zb = zpb[p];
            const v2 zx = {za.x, zb.x}, zy = {za.y, zb.y};
            const v2 zz = {za.z, zb.z}, zw = {za.w, zb.w};

            const v2 xi0 = FMA2(d0, zx, mu[0]);
            const v2 xi1 = FMA2(d1, zy, FMA2(L10, zx, mu[1]));
            const v2 xi2 = FMA2(d2, zz, FMA2(L21, zy, FMA2(L20, zx, mu[2])));
            const v2 xi3 = FMA2(d3, zw, FMA2(L32, zz, FMA2(L31, zy, FMA2(L30, zx, mu[3]))));

            const v2 a1 = xi1, a2 = xi1 + xi2, a3 = a2 + xi3;
            float s1x, c1x, s1y, c1y, s2x, c2x, s2y, c2y, s3x, c3x, s3y, c3y;
            __sincosf(a1.x, &s1x, &c1x);
            __sincosf(a1.y, &s1y, &c1y);
            __sincosf(a2.x, &s2x, &c2x);
            __sincosf(a2.y, &s2y, &c2y);
            __sincosf(a3.x, &s3x, &c3x);
            __sincosf(a3.y, &s3y, &c3y);
            const v2 s1 = {s1x, s1y}, c1 = {c1x, c1y};
            const v2 s2 = {s2x, s2y}, c2 = {c2x, c2y};
            const v2 s3 = {s3x, s3y}, c3 = {c3x, c3y};

            const v2 half = splat(0.5f);
            const v2 px = FMA2(half, c1, FMA2(half, c2, c3));
            const v2 py = xi0 + FMA2(half, s1, FMA2(half, s2, s3));

            const v2 q0 = xi0 * splat(4.0f), q1 = xi1 * splat(2.0f);
            const v2 q2 = xi2 * splat(2.0f), q3 = xi3 * splat(2.0f);
            const v2 pq = FMA2(q0, q0, FMA2(q1, q1, FMA2(q2, q2, q3 * q3)));
            const v2 r0 = (Y0 - px) * splat(100.0f);
            const v2 r1 = (Y1 - py) * splat(100.0f);
            acc = FMA2(splat(-0.5f), pq + FMA2(r0, r0, r1 * r1), acc);
        }
        if (nb < N) {
            rv = fmaf(0.125f, acc.x, C_ALL + __logf(prod.x))
               + fmaf(0.125f, acc.y, C_ALL + __logf(prod.y));
        } else {
            rv = fmaf(0.125f, acc.x, C_ALL + __logf(prod.x));
        }
    }

    // wave (64) shuffle reduce, then cross-wave via LDS (2 waves)
#pragma unroll
    for (int d = 32; d > 0; d >>= 1) rv += __shfl_down(rv, d);
    if ((tid & 63) == 0) wsum[tid >> 6] = rv;
    __syncthreads();
    if (tid == 0) {
        atomicAdd(out, (wsum[0] + wsum[1]) * invN);
    }
}

extern "C" void kernel_launch(void* const* d_in, const int* in_sizes, int n_in,
                              void* d_out, int out_size, void* d_ws, size_t ws_size,
                              hipStream_t stream) {
    const float* y = (const float*)d_in[0];
    const float* zs = (const float*)d_in[1];
    WPtrs wp;
    for (int i = 0; i < 18; ++i) wp.p[i] = (const float*)d_in[2 + i];
    float* out = (float*)d_out;
    const int N = in_sizes[0] / 2;

    hipMemsetAsync(out, 0, sizeof(float), stream);
    const int blocks = (N + 255) / 256;   // 2 rows per thread, 128 threads/block
    avi_kernel<<<blocks, 128, 0, stream>>>(y, zs, wp, out, N, 1.0f / (float)N);
}

// Round 11
// 159.256 us; speedup vs baseline: 1.1519x; 1.0585x over previous
//
#include <hip/hip_runtime.h>
#include <math.h>

// Amortized VI: per-row 3 MLPs (2->20->10->{4,4,6}), Cholesky reparam over
// P=8 samples, robot-arm FK likelihood, global mean.
//
// R9 model (fits whole ladder): per-wave serial s_load weight stream, ~60
// batches x ~250cy K$/L2 latency; consumption per batch at R rows/thread
// (packed) = 64R cyc. R=2 -> 50% stall (R6 37us). R=4 -> self-covering.
// Fused R=4 (R8's split poisoned this test with ws round-trip). Grid 512
// blocks = 2 waves/SIMD resident -> VGPR up to 256 free (m69), so both z
// prefetch banks (128 VGPR) are occupancy-free.
//
// Constants folded: C_PRIOR + C_LIK + C_ENT = 12.838199208
#define C_ALL 12.838199208f

typedef float v2 __attribute__((ext_vector_type(2)));
static __device__ __forceinline__ v2 splat(float s) { return (v2){s, s}; }
#define FMA2 __builtin_elementwise_fma
#define MAX2 __builtin_elementwise_max

struct WPtrs { const float* p[18]; };

__device__ __forceinline__ float softplus_f(float x) {
    return fmaxf(x, 0.0f) + __logf(1.0f + __expf(-fabsf(x)));
}
__device__ __forceinline__ v2 sp2(v2 x) {
    v2 r; r.x = softplus_f(x.x); r.y = softplus_f(x.y); return r;
}

// 4-row MLP (two packed v2 pairs); every scalar weight feeds 4 FMAs (2 VOP3P).
template <int OD>
__device__ __forceinline__ void mlp4(const float* __restrict__ W1,
                                     const float* __restrict__ b1,
                                     const float* __restrict__ W2,
                                     const float* __restrict__ b2,
                                     const float* __restrict__ W3,
                                     const float* __restrict__ b3,
                                     v2 Y0a, v2 Y1a, v2 Y0b, v2 Y1b,
                                     v2* oa, v2* ob) {
    v2 h2a[10], h2b[10];
#pragma unroll
    for (int k = 0; k < 10; ++k) { const v2 bb = splat(b2[k]); h2a[k] = bb; h2b[k] = bb; }
#pragma unroll
    for (int j = 0; j < 20; ++j) {
        const float w0 = W1[j], w1 = W1[20 + j], bb = b1[j];
        const v2 h1a = MAX2(FMA2(Y0a, splat(w0), FMA2(Y1a, splat(w1), splat(bb))), splat(0.0f));
        const v2 h1b = MAX2(FMA2(Y0b, splat(w0), FMA2(Y1b, splat(w1), splat(bb))), splat(0.0f));
#pragma unroll
        for (int k = 0; k < 10; ++k) {
            const v2 w = splat(W2[j * 10 + k]);
            h2a[k] = FMA2(h1a, w, h2a[k]);
            h2b[k] = FMA2(h1b, w, h2b[k]);
        }
    }
#pragma unroll
    for (int k = 0; k < 10; ++k) { h2a[k] = MAX2(h2a[k], splat(0.0f)); h2b[k] = MAX2(h2b[k], splat(0.0f)); }
#pragma unroll
    for (int d = 0; d < OD; ++d) { const v2 bb = splat(b3[d]); oa[d] = bb; ob[d] = bb; }
#pragma unroll
    for (int k = 0; k < 10; ++k) {
#pragma unroll
        for (int d = 0; d < OD; ++d) {
            const v2 w = splat(W3[k * OD + d]);
            oa[d] = FMA2(h2a[k], w, oa[d]);
            ob[d] = FMA2(h2b[k], w, ob[d]);
        }
    }
}

// packed 2-row tail over the 8 samples (z in registers)
__device__ __forceinline__ v2 tail_pack(const v2* mu, v2 d0, v2 d1, v2 d2, v2 d3,
                                        const v2* lo, v2 Y0, v2 Y1,
                                        const float4* z1, const float4* z2) {
    const v2 L10 = lo[0], L20 = lo[1], L21 = lo[2];
    const v2 L30 = lo[3], L31 = lo[4], L32 = lo[5];
    v2 acc = splat(0.0f);
#pragma unroll
    for (int p = 0; p < 8; ++p) {
        const v2 zx = {z1[p].x, z2[p].x}, zy = {z1[p].y, z2[p].y};
        const v2 zz = {z1[p].z, z2[p].z}, zw = {z1[p].w, z2[p].w};

        const v2 xi0 = FMA2(d0, zx, mu[0]);
        const v2 xi1 = FMA2(d1, zy, FMA2(L10, zx, mu[1]));
        const v2 xi2 = FMA2(d2, zz, FMA2(L21, zy, FMA2(L20, zx, mu[2])));
        const v2 xi3 = FMA2(d3, zw, FMA2(L32, zz, FMA2(L31, zy, FMA2(L30, zx, mu[3]))));

        const v2 a1 = xi1, a2 = xi1 + xi2, a3 = a2 + xi3;
        float s1x, c1x, s1y, c1y, s2x, c2x, s2y, c2y, s3x, c3x, s3y, c3y;
        __sincosf(a1.x, &s1x, &c1x);
        __sincosf(a1.y, &s1y, &c1y);
        __sincosf(a2.x, &s2x, &c2x);
        __sincosf(a2.y, &s2y, &c2y);
        __sincosf(a3.x, &s3x, &c3x);
        __sincosf(a3.y, &s3y, &c3y);
        const v2 s1 = {s1x, s1y}, c1 = {c1x, c1y};
        const v2 s2 = {s2x, s2y}, c2 = {c2x, c2y};
        const v2 s3 = {s3x, s3y}, c3 = {c3x, c3y};

        const v2 half = splat(0.5f);
        const v2 px = FMA2(half, c1, FMA2(half, c2, c3));
        const v2 py = xi0 + FMA2(half, s1, FMA2(half, s2, s3));

        const v2 q0 = xi0 * splat(4.0f), q1 = xi1 * splat(2.0f);
        const v2 q2 = xi2 * splat(2.0f), q3 = xi3 * splat(2.0f);
        const v2 pq = FMA2(q0, q0, FMA2(q1, q1, FMA2(q2, q2, q3 * q3)));
        const v2 r0 = (Y0 - px) * splat(100.0f);
        const v2 r1 = (Y1 - py) * splat(100.0f);
        acc = FMA2(splat(-0.5f), pq + FMA2(r0, r0, r1 * r1), acc);
    }
    return acc;
}

// ---- scalar fallback (tail guard; never hit at N=524288) ----
template <int OD>
__device__ __forceinline__ void mlp1(const float* __restrict__ W1, const float* __restrict__ b1,
                                     const float* __restrict__ W2, const float* __restrict__ b2,
                                     const float* __restrict__ W3, const float* __restrict__ b3,
                                     float y0, float y1, float* out) {
    float h2[10];
#pragma unroll
    for (int k = 0; k < 10; ++k) h2[k] = b2[k];
#pragma unroll
    for (int j = 0; j < 20; ++j) {
        const float h1 = fmaxf(0.0f, fmaf(y0, W1[j], fmaf(y1, W1[20 + j], b1[j])));
#pragma unroll
        for (int k = 0; k < 10; ++k) h2[k] = fmaf(h1, W2[j * 10 + k], h2[k]);
    }
#pragma unroll
    for (int k = 0; k < 10; ++k) h2[k] = fmaxf(0.0f, h2[k]);
#pragma unroll
    for (int d = 0; d < OD; ++d) out[d] = b3[d];
#pragma unroll
    for (int k = 0; k < 10; ++k)
#pragma unroll
        for (int d = 0; d < OD; ++d) out[d] = fmaf(h2[k], W3[k * OD + d], out[d]);
}

__device__ float row_scalar(const float* __restrict__ y, const float* __restrict__ zs,
                            const WPtrs& wp, int n) {
    const float2 yv = *reinterpret_cast<const float2*>(y + 2 * (size_t)n);
    const float y0 = yv.x, y1 = yv.y;
    float mu[4], ld[4], lo[6];
    mlp1<4>(wp.p[0], wp.p[1], wp.p[2], wp.p[3], wp.p[4], wp.p[5], y0, y1, mu);
    mlp1<4>(wp.p[6], wp.p[7], wp.p[8], wp.p[9], wp.p[10], wp.p[11], y0, y1, ld);
    mlp1<6>(wp.p[12], wp.p[13], wp.p[14], wp.p[15], wp.p[16], wp.p[17], y0, y1, lo);
    const float d0 = softplus_f(ld[0]), d1 = softplus_f(ld[1]);
    const float d2 = softplus_f(ld[2]), d3 = softplus_f(ld[3]);
    const float slog = __logf(d0 * d1 * d2 * d3);
    const float4* zp = reinterpret_cast<const float4*>(zs + (size_t)n * 32);
    float acc = 0.0f;
    for (int p = 0; p < 8; ++p) {
        const float4 z = zp[p];
        const float xi0 = fmaf(d0, z.x, mu[0]);
        const float xi1 = fmaf(d1, z.y, fmaf(lo[0], z.x, mu[1]));
        const float xi2 = fmaf(d2, z.z, fmaf(lo[2], z.y, fmaf(lo[1], z.x, mu[2])));
        const float xi3 = fmaf(d3, z.w, fmaf(lo[5], z.z, fmaf(lo[4], z.y, fmaf(lo[3], z.x, mu[3]))));
        const float a1 = xi1, a2 = xi1 + xi2, a3 = a2 + xi3;
        float s1, c1, s2, c2, s3, c3;
        __sincosf(a1, &s1, &c1); __sincosf(a2, &s2, &c2); __sincosf(a3, &s3, &c3);
        const float px = fmaf(0.5f, c1, fmaf(0.5f, c2, c3));
        const float py = xi0 + fmaf(0.5f, s1, fmaf(0.5f, s2, s3));
        const float q0 = xi0 * 4.0f, q1 = xi1 * 2.0f, q2 = xi2 * 2.0f, q3 = xi3 * 2.0f;
        const float pq = fmaf(q0, q0, fmaf(q1, q1, fmaf(q2, q2, q3 * q3)));
        const float r0 = (y0 - px) * 100.0f;
        const float r1 = (y1 - py) * 100.0f;
        acc = fmaf(-0.5f, pq + fmaf(r0, r0, r1 * r1), acc);
    }
    return fmaf(0.125f, acc, C_ALL + slog);
}

__global__ __launch_bounds__(256, 2) void avi_kernel(
    const float* __restrict__ y, const float* __restrict__ zs, WPtrs wp,
    float* __restrict__ out, int N, float invN) {
    __shared__ float wsum[4];

    const int tid = threadIdx.x;
    const int r0 = blockIdx.x * 1024 + tid;  // rows r0, +256, +512, +768
    float rv = 0.0f;
    if (r0 + 768 < N) {
        const float2 ya1 = *reinterpret_cast<const float2*>(y + 2 * (size_t)r0);
        const float2 ya2 = *reinterpret_cast<const float2*>(y + 2 * (size_t)(r0 + 256));
        const float2 yb1 = *reinterpret_cast<const float2*>(y + 2 * (size_t)(r0 + 512));
        const float2 yb2 = *reinterpret_cast<const float2*>(y + 2 * (size_t)(r0 + 768));

        // ---- prefetch bank A (rows r0, r0+256): 16 float4, covered by MLPs ----
        const float4* zp_a1 = reinterpret_cast<const float4*>(zs + (size_t)r0 * 32);
        const float4* zp_a2 = reinterpret_cast<const float4*>(zs + (size_t)(r0 + 256) * 32);
        float4 za1[8], za2[8];
#pragma unroll
        for (int p = 0; p < 8; ++p) { za1[p] = zp_a1[p]; za2[p] = zp_a2[p]; }
        __builtin_amdgcn_sched_barrier(0);

        const v2 Y0a = {ya1.x, ya2.x}, Y1a = {ya1.y, ya2.y};
        const v2 Y0b = {yb1.x, yb2.x}, Y1b = {yb1.y, yb2.y};

        v2 mua[4], mub[4], lda[4], ldb[4], loa[6], lob[6];
        mlp4<4>(wp.p[0], wp.p[1], wp.p[2], wp.p[3], wp.p[4], wp.p[5],
                Y0a, Y1a, Y0b, Y1b, mua, mub);
        mlp4<4>(wp.p[6], wp.p[7], wp.p[8], wp.p[9], wp.p[10], wp.p[11],
                Y0a, Y1a, Y0b, Y1b, lda, ldb);
        mlp4<6>(wp.p[12], wp.p[13], wp.p[14], wp.p[15], wp.p[16], wp.p[17],
                Y0a, Y1a, Y0b, Y1b, loa, lob);

        // ---- prefetch bank B (rows r0+512, r0+768): covered by tail-A ----
        const float4* zp_b1 = reinterpret_cast<const float4*>(zs + (size_t)(r0 + 512) * 32);
        const float4* zp_b2 = reinterpret_cast<const float4*>(zs + (size_t)(r0 + 768) * 32);
        float4 zb1[8], zb2[8];
#pragma unroll
        for (int p = 0; p < 8; ++p) { zb1[p] = zp_b1[p]; zb2[p] = zp_b2[p]; }
        __builtin_amdgcn_sched_barrier(0);

        const v2 da0 = sp2(lda[0]), da1 = sp2(lda[1]), da2 = sp2(lda[2]), da3 = sp2(lda[3]);
        const v2 db0 = sp2(ldb[0]), db1 = sp2(ldb[1]), db2 = sp2(ldb[2]), db3 = sp2(ldb[3]);
        const v2 prodA = da0 * da1 * da2 * da3;
        const v2 prodB = db0 * db1 * db2 * db3;

        const v2 accA = tail_pack(mua, da0, da1, da2, da3, loa, Y0a, Y1a, za1, za2);
        const v2 accB = tail_pack(mub, db0, db1, db2, db3, lob, Y0b, Y1b, zb1, zb2);

        rv = fmaf(0.125f, accA.x, C_ALL + __logf(prodA.x))
           + fmaf(0.125f, accA.y, C_ALL + __logf(prodA.y))
           + fmaf(0.125f, accB.x, C_ALL + __logf(prodB.x))
           + fmaf(0.125f, accB.y, C_ALL + __logf(prodB.y));
    } else {
        for (int s = 0; s < 4; ++s) {
            const int row = r0 + s * 256;
            if (row < N) rv += row_scalar(y, zs, wp, row);
        }
    }

    // wave (64) shuffle reduce, then cross-wave via LDS
#pragma unroll
    for (int d = 32; d > 0; d >>= 1) rv += __shfl_down(rv, d);
    if ((tid & 63) == 0) wsum[tid >> 6] = rv;
    __syncthreads();
    if (tid == 0) {
        const float s = wsum[0] + wsum[1] + wsum[2] + wsum[3];
        atomicAdd(out, s * invN);
    }
}

extern "C" void kernel_launch(void* const* d_in, const int* in_sizes, int n_in,
                              void* d_out, int out_size, void* d_ws, size_t ws_size,
                              hipStream_t stream) {
    const float* y = (const float*)d_in[0];
    const float* zs = (const float*)d_in[1];
    WPtrs wp;
    for (int i = 0; i < 18; ++i) wp.p[i] = (const float*)d_in[2 + i];
    float* out = (float*)d_out;
    const int N = in_sizes[0] / 2;

    hipMemsetAsync(out, 0, sizeof(float), stream);
    const int blocks = (N + 1023) / 1024;   // 4 rows/thread, 256 threads/block
    avi_kernel<<<blocks, 256, 0, stream>>>(y, zs, wp, out, N, 1.0f / (float)N);
}